// Round 2
// baseline (602.848 us; speedup 1.0000x reference)
//
#include <hip/hip_runtime.h>

typedef float v2f __attribute__((ext_vector_type(2)));

#define T_LEN 512
#define INP 5
#define HID 32

__device__ __forceinline__ v2f pkfma(v2f a, v2f b, v2f c) {
    return __builtin_elementwise_fma(a, b, c);
}

// 3-wave pipeline per batch element:
//   wave0: layer0 LSTM cell   h0_t = cell0(h0_{t-1}, x_t)          (Whh0 rows in regs)
//   wave1: xp1_t = Wih1 * h0_t + bias1                             (Wih1 rows in regs)
//   wave2: layer1 LSTM cell   h1_t = cell1(h1_{t-1}, xp1_t)        (Whh1 rows in regs)
// Global step s: w0 does t=s, w1 does t=s-1, w2 does t=s-2. One barrier/step.
__global__ __launch_bounds__(192, 4) void lstm2_pipe(
    const float* __restrict__ x,
    const float* __restrict__ Wih0, const float* __restrict__ Whh0,
    const float* __restrict__ bih0, const float* __restrict__ bhh0,
    const float* __restrict__ Wih1, const float* __restrict__ Whh1,
    const float* __restrict__ bih1, const float* __restrict__ bhh1,
    const float* __restrict__ Wfc,  const float* __restrict__ bfc,
    float* __restrict__ out)
{
    const int b   = blockIdx.x;
    const int tid = threadIdx.x;
    const int wid = tid >> 6;          // 0,1,2
    const int l   = tid & 63;
    const int glo = l, ghi = l + 64;   // this lane's two gate rows (of 128)
    const bool isIG = (l < 32);        // lanes<32: (i,g); lanes>=32: (f,o)

    __shared__ __align__(16) float h0buf[2][HID];
    __shared__ __align__(16) float h1buf[2][HID];
    __shared__ __align__(16) float p1buf[2][4 * HID];

    if (tid < HID) { h0buf[1][tid] = 0.0f; h1buf[1][tid] = 0.0f; }

    // ---- per-wave weight rows (same registers, different matrix per wave) ----
    const float* WA = (wid == 0) ? Whh0 : (wid == 1 ? Wih1 : Whh1);
    v2f wlo[16], whi[16];
    {
        const float4* rlo = (const float4*)(WA + glo * HID);
        const float4* rhi = (const float4*)(WA + ghi * HID);
        #pragma unroll
        for (int r = 0; r < 8; ++r) {
            float4 a_ = rlo[r], c_ = rhi[r];
            wlo[2*r]   = (v2f){a_.x, a_.y};
            wlo[2*r+1] = (v2f){a_.z, a_.w};
            whi[2*r]   = (v2f){c_.x, c_.y};
            whi[2*r+1] = (v2f){c_.z, c_.w};
        }
    }

    float biaslo = 0.0f, biashi = 0.0f;
    if (wid == 0) { biaslo = bih0[glo] + bhh0[glo]; biashi = bih0[ghi] + bhh0[ghi]; }
    if (wid == 1) { biaslo = bih1[glo] + bhh1[glo]; biashi = bih1[ghi] + bhh1[ghi]; }

    // layer-0 input weights (wave0 only)
    v2f wxlo01 = (v2f)0.0f, wxlo23 = (v2f)0.0f, wxhi01 = (v2f)0.0f, wxhi23 = (v2f)0.0f;
    float wxlo4 = 0.0f, wxhi4 = 0.0f;
    if (wid == 0) {
        const float* rl = Wih0 + glo * INP;
        const float* rh = Wih0 + ghi * INP;
        wxlo01 = (v2f){rl[0], rl[1]}; wxlo23 = (v2f){rl[2], rl[3]}; wxlo4 = rl[4];
        wxhi01 = (v2f){rh[0], rh[1]}; wxhi23 = (v2f){rh[2], rh[3]}; wxhi4 = rh[4];
    }

    // activation constants for the "hi" gate: tanh (g) on lanes<32, sigmoid (o) on lanes>=32
    const float kk_hi = isIG ? -2.0f : -1.0f;
    const float sc_hi = isIG ?  2.0f :  1.0f;
    const float bb_hi = isIG ? -1.0f :  0.0f;

    float cst = 0.0f;     // c0 (wave0) / c1 (wave2)
    float hlast = 0.0f;   // wave2's running h1

    const float* xb = x + (size_t)b * T_LEN * INP;
    float xa0 = 0.f, xa1 = 0.f, xa2 = 0.f, xa3 = 0.f, xa4 = 0.f;
    if (wid == 0) { xa0 = xb[0]; xa1 = xb[1]; xa2 = xb[2]; xa3 = xb[3]; xa4 = xb[4]; }

    __syncthreads();

#define DOT16(HSRC, GL, GH) { \
    v2f aL0 = (v2f)0.0f, aL1 = (v2f)0.0f, aH0 = (v2f)0.0f, aH1 = (v2f)0.0f; \
    const float4* h4_ = (const float4*)(HSRC); \
    _Pragma("unroll") \
    for (int r = 0; r < 8; ++r) { \
        float4 hq = h4_[r]; \
        v2f hp0 = (v2f){hq.x, hq.y}; \
        v2f hp1 = (v2f){hq.z, hq.w}; \
        aL0 = pkfma(wlo[2*r],   hp0, aL0); \
        aL1 = pkfma(wlo[2*r+1], hp1, aL1); \
        aH0 = pkfma(whi[2*r],   hp0, aH0); \
        aH1 = pkfma(whi[2*r+1], hp1, aH1); \
    } \
    GL = (aL0.x + aL1.x) + (aL0.y + aL1.y); \
    GH = (aH0.x + aH1.x) + (aH0.y + aH1.y); \
}

    for (int s = 0; s < T_LEN + 2; ++s) {
        if (wid == 0) {
            if (s < T_LEN) {
                float gl, gh;
                DOT16(h0buf[(s + 1) & 1], gl, gh);     // h0_{s-1}
                // input contribution
                v2f xv01 = (v2f){xa0, xa1}, xv23 = (v2f){xa2, xa3};
                v2f tl = pkfma(wxlo01, xv01, pkfma(wxlo23, xv23, (v2f)0.0f));
                v2f th_ = pkfma(wxhi01, xv01, pkfma(wxhi23, xv23, (v2f)0.0f));
                gl += biaslo + tl.x + tl.y + wxlo4 * xa4;
                gh += biashi + th_.x + th_.y + wxhi4 * xa4;

                float actL = __builtin_amdgcn_rcpf(1.0f + __expf(-gl));
                float actH = fmaf(sc_hi, __builtin_amdgcn_rcpf(1.0f + __expf(kk_hi * gh)), bb_hi);
                float actLs = __shfl_xor(actL, 32);
                float actHs = __shfl_xor(actH, 32);
                float i_ = isIG ? actL  : actLs;
                float f_ = isIG ? actLs : actL;
                float g_ = isIG ? actH  : actHs;
                float o_ = isIG ? actHs : actH;
                cst = fmaf(f_, cst, i_ * g_);
                float th0 = fmaf(2.0f, __builtin_amdgcn_rcpf(1.0f + __expf(-2.0f * cst)), -1.0f);
                float hnew = o_ * th0;
                if (l < HID) h0buf[s & 1][l] = hnew;
                if (s + 1 < T_LEN) {
                    const float* xp = xb + (s + 1) * INP;
                    xa0 = xp[0]; xa1 = xp[1]; xa2 = xp[2]; xa3 = xp[3]; xa4 = xp[4];
                }
            }
        } else if (wid == 1) {
            if (s >= 1 && s <= T_LEN) {
                float pl, ph;
                DOT16(h0buf[(s + 1) & 1], pl, ph);     // h0_{s-1} (same buffer w0 reads)
                pl += biaslo; ph += biashi;
                p1buf[(s + 1) & 1][glo] = pl;
                p1buf[(s + 1) & 1][ghi] = ph;
            }
        } else {
            if (s >= 2) {
                const int t2 = s - 2;                  // t2 <= T_LEN-1
                float gl = p1buf[t2 & 1][glo];
                float gh = p1buf[t2 & 1][ghi];
                float dl, dh;
                DOT16(h1buf[(t2 + 1) & 1], dl, dh);    // h1_{t2-1}
                gl += dl; gh += dh;

                float actL = __builtin_amdgcn_rcpf(1.0f + __expf(-gl));
                float actH = fmaf(sc_hi, __builtin_amdgcn_rcpf(1.0f + __expf(kk_hi * gh)), bb_hi);
                float actLs = __shfl_xor(actL, 32);
                float actHs = __shfl_xor(actH, 32);
                float i_ = isIG ? actL  : actLs;
                float f_ = isIG ? actLs : actL;
                float g_ = isIG ? actH  : actHs;
                float o_ = isIG ? actHs : actH;
                cst = fmaf(f_, cst, i_ * g_);
                float th1 = fmaf(2.0f, __builtin_amdgcn_rcpf(1.0f + __expf(-2.0f * cst)), -1.0f);
                hlast = o_ * th1;
                if (l < HID) h1buf[t2 & 1][l] = hlast;
            }
        }
        __syncthreads();
    }

    // ---- final linear head (wave2 holds h1_{T-1}) ----
    if (wid == 2) {
        const int m = l & 31;
        float p0 = isIG ? (Wfc[m]       * hlast) : 0.0f;
        float p1 = isIG ? (Wfc[HID + m] * hlast) : 0.0f;
        #pragma unroll
        for (int off = 32; off >= 1; off >>= 1) {
            p0 += __shfl_xor(p0, off);
            p1 += __shfl_xor(p1, off);
        }
        if (l == 0) {
            out[2 * b + 0] = p0 + bfc[0];
            out[2 * b + 1] = p1 + bfc[1];
        }
    }
#undef DOT16
}

extern "C" void kernel_launch(void* const* d_in, const int* in_sizes, int n_in,
                              void* d_out, int out_size, void* d_ws, size_t ws_size,
                              hipStream_t stream) {
    const float* x    = (const float*)d_in[0];
    const float* Wih0 = (const float*)d_in[1];
    const float* Whh0 = (const float*)d_in[2];
    const float* bih0 = (const float*)d_in[3];
    const float* bhh0 = (const float*)d_in[4];
    const float* Wih1 = (const float*)d_in[5];
    const float* Whh1 = (const float*)d_in[6];
    const float* bih1 = (const float*)d_in[7];
    const float* bhh1 = (const float*)d_in[8];
    const float* Wfc  = (const float*)d_in[9];
    const float* bfc  = (const float*)d_in[10];
    float* out = (float*)d_out;

    const int nb = in_sizes[0] / (T_LEN * INP);   // 2048 batch elements
    lstm2_pipe<<<dim3(nb), dim3(192), 0, stream>>>(
        x, Wih0, Whh0, bih0, bhh0, Wih1, Whh1, bih1, bhh1, Wfc, bfc, out);
}

// Round 3
// 505.380 us; speedup vs baseline: 1.1929x; 1.1929x over previous
//
#include <hip/hip_runtime.h>

typedef float v2f __attribute__((ext_vector_type(2)));
typedef float v4f __attribute__((ext_vector_type(4)));

#define T_LEN 512
#define INP 5
#define HID 32
#define XPAD 8   // padded x row stride (floats) so float4 reads stay 16B-aligned

__device__ __forceinline__ v2f pkfma(v2f a, v2f b, v2f c) {
    return __builtin_elementwise_fma(a, b, c);
}

// One wave per batch element. Whole x[b] staged in LDS; weights register-resident.
__global__ __launch_bounds__(64, 2) void lstm2_fused(
    const float* __restrict__ x,
    const float* __restrict__ Wih0, const float* __restrict__ Whh0,
    const float* __restrict__ bih0, const float* __restrict__ bhh0,
    const float* __restrict__ Wih1, const float* __restrict__ Whh1,
    const float* __restrict__ bih1, const float* __restrict__ bhh1,
    const float* __restrict__ Wfc,  const float* __restrict__ bfc,
    float* __restrict__ out)
{
    const int b = blockIdx.x;
    const int l = threadIdx.x;        // 0..63
    const int glo = l, ghi = l + 64;  // this lane's two gate rows (of 128)
    const bool isIG = (l < 32);       // lanes<32: (i,g); lanes>=32: (f,o)

    __shared__ __align__(16) float xs[T_LEN][XPAD];   // 16 KB staged input
    __shared__ __align__(16) float h0s[HID];
    __shared__ __align__(16) float h1s[HID];

    // ---- stage x[b] into LDS, coalesced ----
    const float* xb = x + (size_t)b * (T_LEN * INP);
    for (int idx = l; idx < T_LEN * INP; idx += 64) {
        const int t = idx / INP;              // magic-mul div
        const int d = idx - t * INP;
        xs[t][d] = xb[idx];
    }

    // ---- weights register-resident, packed over j-pairs ----
    v2f whh0_lo[16], whh0_hi[16], wih1_lo[16], wih1_hi[16], whh1_lo[16], whh1_hi[16];
#define LOADW(dst_lo, dst_hi, W) { \
    const v4f* rlo_ = (const v4f*)((W) + glo * HID); \
    const v4f* rhi_ = (const v4f*)((W) + ghi * HID); \
    _Pragma("unroll") \
    for (int r = 0; r < 8; ++r) { \
        v4f a_ = rlo_[r], c_ = rhi_[r]; \
        dst_lo[2*r]   = __builtin_shufflevector(a_, a_, 0, 1); \
        dst_lo[2*r+1] = __builtin_shufflevector(a_, a_, 2, 3); \
        dst_hi[2*r]   = __builtin_shufflevector(c_, c_, 0, 1); \
        dst_hi[2*r+1] = __builtin_shufflevector(c_, c_, 2, 3); \
    } }
    LOADW(whh0_lo, whh0_hi, Whh0)
    LOADW(wih1_lo, wih1_hi, Wih1)
    LOADW(whh1_lo, whh1_hi, Whh1)
#undef LOADW

    v2f wxlo01, wxlo23, wxhi01, wxhi23;
    float wxlo4, wxhi4;
    {
        const float* rl = Wih0 + glo * INP;
        const float* rh = Wih0 + ghi * INP;
        wxlo01 = (v2f){rl[0], rl[1]}; wxlo23 = (v2f){rl[2], rl[3]}; wxlo4 = rl[4];
        wxhi01 = (v2f){rh[0], rh[1]}; wxhi23 = (v2f){rh[2], rh[3]}; wxhi4 = rh[4];
    }

    const float bias0_lo = bih0[glo] + bhh0[glo];
    const float bias0_hi = bih0[ghi] + bhh0[ghi];
    const float bias1_lo = bih1[glo] + bhh1[glo];
    const float bias1_hi = bih1[ghi] + bhh1[ghi];

    // activations via exp2 with pre-scaled constants:
    //   sigmoid(v) = rcp(1 + exp2(-log2e * v))
    //   tanh(v)    = 2*rcp(1 + exp2(-2*log2e * v)) - 1
    const float NL2E  = -1.4426950408889634f;   // -log2(e)
    const float NL2E2 = -2.8853900817779268f;   // -2*log2(e)
    const float kk_hi = isIG ? NL2E2 : NL2E;    // g: tanh, o: sigmoid
    const float sc_hi = isIG ?  2.0f : 1.0f;
    const float bb_hi = isIG ? -1.0f : 0.0f;

    float c0 = 0.0f, c1 = 0.0f, h1last = 0.0f;
    if (l < HID) { h0s[l] = 0.0f; h1s[l] = 0.0f; }
    __syncthreads();

    const v4f* h04 = (const v4f*)h0s;
    const v4f* h14 = (const v4f*)h1s;

#define RED(a0, a1) ({ v2f s_ = (a0) + (a1); s_.x + s_.y; })

    for (int t = 0; t < T_LEN; ++t) {
        // ---- x_t from LDS (uniform broadcast reads) ----
        v4f xq = *(const v4f*)&xs[t][0];
        float x4 = xs[t][4];
        v2f xv01 = __builtin_shufflevector(xq, xq, 0, 1);
        v2f xv23 = __builtin_shufflevector(xq, xq, 2, 3);

        // ================= layer 0 =================
        v2f aL0 = pkfma(wxlo01, xv01, (v2f){bias0_lo, 0.0f});
        v2f aL1 = pkfma(wxlo23, xv23, (v2f){wxlo4 * x4, 0.0f});
        v2f aH0 = pkfma(wxhi01, xv01, (v2f){bias0_hi, 0.0f});
        v2f aH1 = pkfma(wxhi23, xv23, (v2f){wxhi4 * x4, 0.0f});
        #pragma unroll
        for (int r = 0; r < 8; ++r) {
            v4f hq = h04[r];                         // h0_{t-1}, uniform b128
            v2f hp0 = __builtin_shufflevector(hq, hq, 0, 1);
            v2f hp1 = __builtin_shufflevector(hq, hq, 2, 3);
            aL0 = pkfma(whh0_lo[2*r],   hp0, aL0);
            aL1 = pkfma(whh0_lo[2*r+1], hp1, aL1);
            aH0 = pkfma(whh0_hi[2*r],   hp0, aH0);
            aH1 = pkfma(whh0_hi[2*r+1], hp1, aH1);
        }
        float gl = RED(aL0, aL1);
        float gh = RED(aH0, aH1);

        float actL = __builtin_amdgcn_rcpf(1.0f + exp2f(NL2E * gl));             // sigmoid
        float actH = fmaf(sc_hi, __builtin_amdgcn_rcpf(1.0f + exp2f(kk_hi * gh)), bb_hi);
        float actLs = __shfl_xor(actL, 32);
        float actHs = __shfl_xor(actH, 32);
        float i_ = isIG ? actL  : actLs;
        float f_ = isIG ? actLs : actL;
        float g_ = isIG ? actH  : actHs;
        float o_ = isIG ? actHs : actH;
        c0 = fmaf(f_, c0, i_ * g_);
        float th0 = fmaf(2.0f, __builtin_amdgcn_rcpf(1.0f + exp2f(NL2E2 * c0)), -1.0f);
        float h0new = o_ * th0;
        if (l < HID) h0s[l] = h0new;
        __syncthreads();

        // ================= layer 1 =================
        v2f bL0 = (v2f){bias1_lo, 0.0f}, bL1 = (v2f)0.0f;
        v2f bH0 = (v2f){bias1_hi, 0.0f}, bH1 = (v2f)0.0f;
        #pragma unroll
        for (int r = 0; r < 8; ++r) {
            v4f hq = h04[r];                         // h0_t (fresh)
            v2f hp0 = __builtin_shufflevector(hq, hq, 0, 1);
            v2f hp1 = __builtin_shufflevector(hq, hq, 2, 3);
            bL0 = pkfma(wih1_lo[2*r],   hp0, bL0);
            bL1 = pkfma(wih1_lo[2*r+1], hp1, bL1);
            bH0 = pkfma(wih1_hi[2*r],   hp0, bH0);
            bH1 = pkfma(wih1_hi[2*r+1], hp1, bH1);
        }
        #pragma unroll
        for (int r = 0; r < 8; ++r) {
            v4f hq = h14[r];                         // h1_{t-1}
            v2f hp0 = __builtin_shufflevector(hq, hq, 0, 1);
            v2f hp1 = __builtin_shufflevector(hq, hq, 2, 3);
            bL0 = pkfma(whh1_lo[2*r],   hp0, bL0);
            bL1 = pkfma(whh1_lo[2*r+1], hp1, bL1);
            bH0 = pkfma(whh1_hi[2*r],   hp0, bH0);
            bH1 = pkfma(whh1_hi[2*r+1], hp1, bH1);
        }
        float gl1 = RED(bL0, bL1);
        float gh1 = RED(bH0, bH1);

        float actL1 = __builtin_amdgcn_rcpf(1.0f + exp2f(NL2E * gl1));
        float actH1 = fmaf(sc_hi, __builtin_amdgcn_rcpf(1.0f + exp2f(kk_hi * gh1)), bb_hi);
        float actL1s = __shfl_xor(actL1, 32);
        float actH1s = __shfl_xor(actH1, 32);
        float i1 = isIG ? actL1  : actL1s;
        float f1 = isIG ? actL1s : actL1;
        float g1 = isIG ? actH1  : actH1s;
        float o1 = isIG ? actH1s : actH1;
        c1 = fmaf(f1, c1, i1 * g1);
        float th1 = fmaf(2.0f, __builtin_amdgcn_rcpf(1.0f + exp2f(NL2E2 * c1)), -1.0f);
        h1last = o1 * th1;
        if (l < HID) h1s[l] = h1last;
        __syncthreads();
    }
#undef RED

    // ---- final linear head ----
    const int m = l & 31;
    float p0 = isIG ? (Wfc[m]       * h1last) : 0.0f;
    float p1 = isIG ? (Wfc[HID + m] * h1last) : 0.0f;
    #pragma unroll
    for (int off = 32; off >= 1; off >>= 1) {
        p0 += __shfl_xor(p0, off);
        p1 += __shfl_xor(p1, off);
    }
    if (l == 0) {
        out[2 * b + 0] = p0 + bfc[0];
        out[2 * b + 1] = p1 + bfc[1];
    }
}

extern "C" void kernel_launch(void* const* d_in, const int* in_sizes, int n_in,
                              void* d_out, int out_size, void* d_ws, size_t ws_size,
                              hipStream_t stream) {
    const float* x    = (const float*)d_in[0];
    const float* Wih0 = (const float*)d_in[1];
    const float* Whh0 = (const float*)d_in[2];
    const float* bih0 = (const float*)d_in[3];
    const float* bhh0 = (const float*)d_in[4];
    const float* Wih1 = (const float*)d_in[5];
    const float* Whh1 = (const float*)d_in[6];
    const float* bih1 = (const float*)d_in[7];
    const float* bhh1 = (const float*)d_in[8];
    const float* Wfc  = (const float*)d_in[9];
    const float* bfc  = (const float*)d_in[10];
    float* out = (float*)d_out;

    const int nb = in_sizes[0] / (T_LEN * INP);   // 2048 batch elements
    lstm2_fused<<<dim3(nb), dim3(64), 0, stream>>>(
        x, Wih0, Whh0, bih0, bhh0, Wih1, Whh1, bih1, bhh1, Wfc, bfc, out);
}